// Round 7
// baseline (492.684 us; speedup 1.0000x reference)
//
#include <hip/hip_runtime.h>
#include <math.h>

#define VOCAB   128000
#define VOCAB4  32000            // float4 per row
#define NROW    256
#define TOPC    63
#define QPR     4                // blocks per row
#define BS      512
#define Q4      (VOCAB4 / QPR)   // 8000 float4 per quarter
#define TAILT   (Q4 - 15 * BS)   // 320
#define LCAP    256              // per-block LDS candidate cap (E~95, sd~10)
#define CAP     512              // per-row global cap (E~381, sd~20)
#define T0      11.0f            // collect threshold; top-63 cutoff ~13.2

typedef float f32x4 __attribute__((ext_vector_type(4)));

// ws: [0) u32 cnt[NROW] | [1024) u32 arrive[NROW] | [2048) f32 psum[NROW*QPR]
//     [6144) f32 cval[NROW*CAP] | [+512KB) i32 cidx[NROW*CAP]

__device__ __forceinline__ void proc4(
    float4 x, int j4, float inv_t, float4* __restrict__ o4,
    float& s0, float& s1, float& s2, float& s3,
    unsigned int* nc, float* cv, int* ci)
{
  float vx = x.x*inv_t, vy = x.y*inv_t, vz = x.z*inv_t, vw = x.w*inv_t;
  f32x4 v = {vx, vy, vz, vw};
  *(f32x4*)&o4[j4] = v;
  s0 += __expf(vx); s1 += __expf(vy); s2 += __expf(vz); s3 += __expf(vw);
  if (x.x > T0) { unsigned q = atomicAdd(nc,1u); if (q<LCAP){cv[q]=vx; ci[q]=4*j4+0;} }
  if (x.y > T0) { unsigned q = atomicAdd(nc,1u); if (q<LCAP){cv[q]=vy; ci[q]=4*j4+1;} }
  if (x.z > T0) { unsigned q = atomicAdd(nc,1u); if (q<LCAP){cv[q]=vz; ci[q]=4*j4+2;} }
  if (x.w > T0) { unsigned q = atomicAdd(nc,1u); if (q<LCAP){cv[q]=vw; ci[q]=4*j4+3;} }
}

__global__ __launch_bounds__(BS, 8) void sampler_kernel(
    const float* __restrict__ logits, const float* __restrict__ temps,
    const float* __restrict__ topps, const float* __restrict__ topks,
    const float* __restrict__ noise, float* __restrict__ out,
    unsigned int* __restrict__ cnt, unsigned int* __restrict__ arrive,
    float* __restrict__ psum, float* __restrict__ cval, int* __restrict__ cidx)
{
  const int blk = blockIdx.x;
  const int row = blk >> 2;
  const int qq  = blk & 3;
  const int tid = threadIdx.x;

  __shared__ float lcv[LCAP]; __shared__ int lci[LCAP];
  __shared__ unsigned int nc_sh, base_sh, arr_sh;
  __shared__ float wsum[BS / 64];

  if (tid == 0) nc_sh = 0u;
  __syncthreads();

  const float temp  = temps[row];
  const float inv_t = 1.0f / ((temp == 0.0f) ? 1.0f : temp);

  const float4* __restrict__ lg4 =
      reinterpret_cast<const float4*>(logits + (size_t)row * VOCAB);
  float4* __restrict__ o4 =
      reinterpret_cast<float4*>(out + NROW + (size_t)row * VOCAB);

  float s0 = 0.f, s1 = 0.f, s2 = 0.f, s3 = 0.f;

  // ---- streaming quarter-row: scale+write, sum-exp, threshold-collect ----
  int j = qq * Q4 + tid;
  #pragma unroll
  for (int g = 0; g < 7; ++g) {            // 7 pairs = 14 iters
    float4 a = lg4[j];
    float4 b = lg4[j + BS];
    proc4(a, j,      inv_t, o4, s0,s1,s2,s3, &nc_sh, lcv, lci);
    proc4(b, j + BS, inv_t, o4, s0,s1,s2,s3, &nc_sh, lcv, lci);
    j += 2 * BS;
  }
  {                                        // 15th iter
    float4 a = lg4[j];
    proc4(a, j, inv_t, o4, s0,s1,s2,s3, &nc_sh, lcv, lci);
  }
  if (tid < TAILT) {                       // tail 320 float4
    int jt = qq * Q4 + 15 * BS + tid;
    float4 a = lg4[jt];
    proc4(a, jt, inv_t, o4, s0,s1,s2,s3, &nc_sh, lcv, lci);
  }

  // ---- block sum-exp reduce -> psum ----
  float s = (s0 + s1) + (s2 + s3);
  #pragma unroll
  for (int off = 32; off > 0; off >>= 1) s += __shfl_down(s, off);
  if ((tid & 63) == 0) wsum[tid >> 6] = s;
  __syncthreads();
  if (tid == 0) {
    float t = 0.f;
    #pragma unroll
    for (int w = 0; w < BS / 64; ++w) t += wsum[w];
    psum[row * QPR + qq] = t;
  }

  // ---- flush LDS candidates to per-row global list (1 atomic per block) ----
  int nloc = ((int)nc_sh < LCAP) ? (int)nc_sh : LCAP;
  if (tid == 0) base_sh = atomicAdd(&cnt[row], (unsigned)nloc);
  __syncthreads();
  unsigned base = base_sh;
  for (int i = tid; i < nloc; i += BS) {
    unsigned p = base + i;
    if (p < CAP) { cval[row * CAP + p] = lcv[i]; cidx[row * CAP + p] = lci[i]; }
  }

  // ---- last-arriver merge handoff ----
  __threadfence();                          // release: candidates + psum visible
  __syncthreads();
  if (tid == 0) arr_sh = atomicAdd(&arrive[row], 1u);
  __syncthreads();
  if (arr_sh != QPR - 1) return;
  __threadfence();                          // acquire

  // ================= merge + sample (one block per row) =================
  __shared__ float cv2[CAP]; __shared__ int ci2[CAP];
  __shared__ float sv[64];   __shared__ int si[64];
  __shared__ float sp_s[64], sc_s[64], noi_s[64];
  __shared__ unsigned int nc2;

  float S = ((psum[row*QPR+0] + psum[row*QPR+1]) +
             (psum[row*QPR+2] + psum[row*QPR+3]));   // fixed order: deterministic
  int total = (int)cnt[row];
  int n = (total < CAP) ? total : CAP;

  if (tid < 64) noi_s[tid] = noise[(size_t)row * VOCAB + tid];
  for (int i = tid; i < n; i += BS) {
    cv2[i] = cval[row * CAP + i];
    ci2[i] = cidx[row * CAP + i];
  }
  __syncthreads();

  // robustness ladder (dead for bench data): rescan full row
  float thr = T0;
  for (int att = 0; att < 4 && (total < TOPC || total > CAP); ++att) {
    thr = (total > CAP) ? (thr + 2.0f) : (thr - 4.0f);
    __syncthreads();
    if (tid == 0) nc2 = 0u;
    __syncthreads();
    const float* __restrict__ lg = logits + (size_t)row * VOCAB;
    for (int k = tid; k < VOCAB; k += BS) {
      float x = lg[k];
      if (x > thr) {
        unsigned p = atomicAdd(&nc2, 1u);
        if (p < CAP) { cv2[p] = x * inv_t; ci2[p] = k; }
      }
    }
    __syncthreads();
    total = (int)nc2;
    n = (total < CAP) ? total : CAP;
  }

  // rank sort by (value desc, index asc): deterministic despite atomics
  if (tid < n) {
    float vi = cv2[tid]; int xi = ci2[tid];
    int r = 0;
    for (int k = 0; k < n; ++k) {
      float vk = cv2[k]; int xk = ci2[k];
      r += (int)((vk > vi) || (vk == vi && xk < xi));
    }
    if (r < 64) { sv[r] = vi; si[r] = xi; }
  }
  __syncthreads();

  const int lim = (n < TOPC) ? n : TOPC;

  if (tid < lim) {
    float sp = __expf(sv[tid]) * (1.0f / S);
    sp_s[tid] = sp;
    float u = noi_s[tid];
    sc_s[tid] = logf(sp) + (-logf(-logf(u)));
  }
  __syncthreads();

  if (tid == 0) {
    const float kk = topks[row];
    const float tp = topps[row];
    float cdf = 0.f, best = -INFINITY; int bestj = 0;
    for (int k = 0; k < lim; ++k) {
      if (((float)k < kk) && (cdf <= tp)) {
        float sc = sc_s[k];
        if (sc > best) { best = sc; bestj = k; }
      }
      cdf += sp_s[k];                      // exclusive cumsum semantics
    }
    int token = (n > 0) ? si[bestj] : 0;
    if (temp == 0.0f && n > 0) token = si[0];
    out[row] = (float)token;
  }
}

extern "C" void kernel_launch(void* const* d_in, const int* in_sizes, int n_in,
                              void* d_out, int out_size, void* d_ws, size_t ws_size,
                              hipStream_t stream) {
  const float* logits = (const float*)d_in[0];
  const float* temps  = (const float*)d_in[1];
  const float* topps  = (const float*)d_in[2];
  const float* topks  = (const float*)d_in[3];
  const float* noise  = (const float*)d_in[4];
  float* out = (float*)d_out;

  char* ws = (char*)d_ws;
  unsigned int* cnt    = (unsigned int*)(ws);
  unsigned int* arrive = (unsigned int*)(ws + 1024);
  float* psum = (float*)(ws + 2048);
  float* cval = (float*)(ws + 6144);
  int*   cidx = (int*)  (ws + 6144 + (size_t)NROW * CAP * 4);

  hipMemsetAsync(ws, 0, 2048, stream);     // zero cnt + arrive each call
  sampler_kernel<<<NROW * QPR, BS, 0, stream>>>(
      logits, temps, topps, topks, noise, out, cnt, arrive, psum, cval, cidx);
}

// Round 8
// 149.801 us; speedup vs baseline: 3.2889x; 3.2889x over previous
//
#include <hip/hip_runtime.h>
#include <math.h>

#define VOCAB   128000
#define VOCAB4  32000            // float4 per row
#define NROW    256
#define TOPC    63
#define HPR     2                // stream blocks per row
#define BS      1024
#define H4      (VOCAB4 / HPR)   // 16000 float4 per half
#define TAILT   (H4 - 15 * BS)   // 640
#define LCAP    320              // per-block LDS cap (E~190, sd~14)
#define CAP     512              // per-row global cap (E~381, sd~20)
#define T0      11.0f            // collect threshold; top-63 cutoff ~13.2
#define BSM     256              // merge block size

typedef float f32x4 __attribute__((ext_vector_type(4)));

// ws: [0) u32 cnt[NROW] | [1024) f32 psum[NROW*HPR] | [4096) f32 cval[NROW*CAP]
//     | [4096+512KB) i32 cidx[NROW*CAP]

__device__ __forceinline__ void proc4(
    float4 x, int j4, float inv_t, float4* __restrict__ o4,
    float& s0, float& s1, float& s2, float& s3,
    unsigned int* nc, float* cv, int* ci)
{
  float vx = x.x*inv_t, vy = x.y*inv_t, vz = x.z*inv_t, vw = x.w*inv_t;
  f32x4 v = {vx, vy, vz, vw};
  *(f32x4*)&o4[j4] = v;
  s0 += __expf(vx); s1 += __expf(vy); s2 += __expf(vz); s3 += __expf(vw);
  // rare branch (p~0.003/elem)
  if (x.x > T0) { unsigned q = atomicAdd(nc,1u); if (q<LCAP){cv[q]=vx; ci[q]=4*j4+0;} }
  if (x.y > T0) { unsigned q = atomicAdd(nc,1u); if (q<LCAP){cv[q]=vy; ci[q]=4*j4+1;} }
  if (x.z > T0) { unsigned q = atomicAdd(nc,1u); if (q<LCAP){cv[q]=vz; ci[q]=4*j4+2;} }
  if (x.w > T0) { unsigned q = atomicAdd(nc,1u); if (q<LCAP){cv[q]=vw; ci[q]=4*j4+3;} }
}

__global__ __launch_bounds__(BS, 8) void stream_kernel(
    const float* __restrict__ logits, const float* __restrict__ temps,
    float* __restrict__ out, unsigned int* __restrict__ cnt,
    float* __restrict__ psum, float* __restrict__ cval, int* __restrict__ cidx)
{
  const int blk = blockIdx.x;
  const int row = blk >> 1;
  const int hh  = blk & 1;
  const int tid = threadIdx.x;

  __shared__ float lcv[LCAP]; __shared__ int lci[LCAP];
  __shared__ float wsum[BS / 64];
  __shared__ unsigned int nc_sh, base_sh;

  if (tid == 0) nc_sh = 0u;
  __syncthreads();

  const float temp  = temps[row];
  const float inv_t = 1.0f / ((temp == 0.0f) ? 1.0f : temp);

  const float4* __restrict__ lg4 =
      reinterpret_cast<const float4*>(logits + (size_t)row * VOCAB);
  float4* __restrict__ o4 =
      reinterpret_cast<float4*>(out + NROW + (size_t)row * VOCAB);

  float s0 = 0.f, s1 = 0.f, s2 = 0.f, s3 = 0.f;

  // ---- stream half-row: scale+write, sum-exp, threshold-collect (R6 body) ----
  int j = hh * H4 + tid;
  #pragma unroll
  for (int g = 0; g < 7; ++g) {            // 7 pairs = 14 iters
    float4 a = lg4[j];
    float4 b = lg4[j + BS];
    proc4(a, j,      inv_t, o4, s0,s1,s2,s3, &nc_sh, lcv, lci);
    proc4(b, j + BS, inv_t, o4, s0,s1,s2,s3, &nc_sh, lcv, lci);
    j += 2 * BS;
  }
  {                                        // 15th iter
    float4 a = lg4[j];
    proc4(a, j, inv_t, o4, s0,s1,s2,s3, &nc_sh, lcv, lci);
  }
  if (tid < TAILT) {                       // tail 640 float4
    int jt = hh * H4 + 15 * BS + tid;
    float4 a = lg4[jt];
    proc4(a, jt, inv_t, o4, s0,s1,s2,s3, &nc_sh, lcv, lci);
  }

  // ---- block sum-exp reduce -> psum (fixed order, deterministic) ----
  float s = (s0 + s1) + (s2 + s3);
  #pragma unroll
  for (int off = 32; off > 0; off >>= 1) s += __shfl_down(s, off);
  if ((tid & 63) == 0) wsum[tid >> 6] = s;
  __syncthreads();
  if (tid == 0) {
    float t = 0.f;
    #pragma unroll
    for (int w = 0; w < BS / 64; ++w) t += wsum[w];
    psum[row * HPR + hh] = t;
    base_sh = atomicAdd(&cnt[row], (nc_sh < (unsigned)LCAP) ? nc_sh : (unsigned)LCAP);
  }
  __syncthreads();

  // ---- coalesced flush of LDS candidates to per-row global list ----
  const int nloc = ((int)nc_sh < LCAP) ? (int)nc_sh : LCAP;
  const unsigned base = base_sh;
  for (int i = tid; i < nloc; i += BS) {
    unsigned p = base + i;
    if (p < CAP) { cval[row * CAP + p] = lcv[i]; cidx[row * CAP + p] = lci[i]; }
  }
  // no fence: the kernel boundary is the coherence point
}

__global__ __launch_bounds__(BSM) void merge_kernel(
    const float* __restrict__ logits, const float* __restrict__ temps,
    const float* __restrict__ topps, const float* __restrict__ topks,
    const float* __restrict__ noise, float* __restrict__ out,
    const unsigned int* __restrict__ cnt, const float* __restrict__ psum,
    const float* __restrict__ cval, const int* __restrict__ cidx)
{
  const int row = blockIdx.x;
  const int tid = threadIdx.x;

  __shared__ float cv2[CAP]; __shared__ int ci2[CAP];
  __shared__ float sv[64];   __shared__ int si[64];
  __shared__ float sp_s[64], sc_s[64], noi_s[64];
  __shared__ unsigned int nc2;

  if (tid < 64) noi_s[tid] = noise[(size_t)row * VOCAB + tid];

  const float temp  = temps[row];
  const float inv_t = 1.0f / ((temp == 0.0f) ? 1.0f : temp);
  const float S = psum[row * HPR + 0] + psum[row * HPR + 1];  // fixed order

  int total = (int)cnt[row];
  int n = (total < CAP) ? total : CAP;
  for (int i = tid; i < n; i += BSM) {
    cv2[i] = cval[row * CAP + i];
    ci2[i] = cidx[row * CAP + i];
  }
  __syncthreads();

  // robustness ladder (dead for bench data): rescan full L3-warm row
  float thr = T0;
  for (int att = 0; att < 4 && (total < TOPC || total > CAP); ++att) {
    thr = (total > CAP) ? (thr + 2.0f) : (thr - 4.0f);
    __syncthreads();
    if (tid == 0) nc2 = 0u;
    __syncthreads();
    const float* __restrict__ lg = logits + (size_t)row * VOCAB;
    for (int k = tid; k < VOCAB; k += BSM) {
      float x = lg[k];
      if (x > thr) {
        unsigned p = atomicAdd(&nc2, 1u);
        if (p < CAP) { cv2[p] = x * inv_t; ci2[p] = k; }
      }
    }
    __syncthreads();
    total = (int)nc2;
    n = (total < CAP) ? total : CAP;
  }

  // rank sort by (value desc, index asc): deterministic despite atomic order
  for (int i = tid; i < n; i += BSM) {
    float vi = cv2[i]; int xi = ci2[i];
    int r = 0;
    for (int k = 0; k < n; ++k) {
      float vk = cv2[k]; int xk = ci2[k];
      r += (int)((vk > vi) || (vk == vi && xk < xi));
    }
    if (r < 64) { sv[r] = vi; si[r] = xi; }
  }
  __syncthreads();

  const int lim = (n < TOPC) ? n : TOPC;

  // parallel per-slot prob + gumbel score
  if (tid < lim) {
    float sp = __expf(sv[tid]) * (1.0f / S);
    sp_s[tid] = sp;
    float u = noi_s[tid];
    sc_s[tid] = logf(sp) + (-logf(-logf(u)));
  }
  __syncthreads();

  // serial 63-step joint-mask scan + argmax
  if (tid == 0) {
    const float kk = topks[row];
    const float tp = topps[row];
    float cdf = 0.f, best = -INFINITY; int bestj = 0;
    for (int k = 0; k < lim; ++k) {
      if (((float)k < kk) && (cdf <= tp)) {
        float sc = sc_s[k];
        if (sc > best) { best = sc; bestj = k; }
      }
      cdf += sp_s[k];                      // exclusive cumsum semantics
    }
    int token = (n > 0) ? si[bestj] : 0;
    if (temp == 0.0f && n > 0) token = si[0];
    out[row] = (float)token;
  }
}

extern "C" void kernel_launch(void* const* d_in, const int* in_sizes, int n_in,
                              void* d_out, int out_size, void* d_ws, size_t ws_size,
                              hipStream_t stream) {
  const float* logits = (const float*)d_in[0];
  const float* temps  = (const float*)d_in[1];
  const float* topps  = (const float*)d_in[2];
  const float* topks  = (const float*)d_in[3];
  const float* noise  = (const float*)d_in[4];
  float* out = (float*)d_out;

  char* ws = (char*)d_ws;
  unsigned int* cnt = (unsigned int*)(ws);
  float* psum = (float*)(ws + 1024);
  float* cval = (float*)(ws + 4096);
  int*   cidx = (int*)  (ws + 4096 + (size_t)NROW * CAP * 4);

  hipMemsetAsync(cnt, 0, 1024, stream);
  stream_kernel<<<NROW * HPR, BS, 0, stream>>>(logits, temps, out, cnt, psum, cval, cidx);
  merge_kernel<<<NROW, BSM, 0, stream>>>(logits, temps, topps, topks, noise, out,
                                         cnt, psum, cval, cidx);
}

// Round 9
// 77.241 us; speedup vs baseline: 6.3786x; 1.9394x over previous
//
#include <hip/hip_runtime.h>
#include <math.h>

#define VOCAB   128000
#define VOCAB4  32000            // float4 per row
#define NROW    256
#define TOPC    63
#define HPR     2                // stream blocks per row
#define BS      1024
#define H4      (VOCAB4 / HPR)   // 16000 float4 per half
#define TAILT   (H4 - 15 * BS)   // 640
#define LCAP    320              // per-block LDS cap (E~190, sd~14)
#define CAP     512              // per-row global cap (E~381, sd~20)
#define T0      11.0f            // collect threshold; top-63 cutoff ~13.2
#define BSM     512              // merge block size (1 candidate per thread)

typedef float f32x4 __attribute__((ext_vector_type(4)));

// ws: [0) u32 cnt[NROW] | [1024) f32 psum[NROW*HPR] | [4096) f32 cval[NROW*CAP]
//     | [4096+512KB) i32 cidx[NROW*CAP]

__device__ __forceinline__ unsigned ordf(float v) {
  unsigned u = __float_as_uint(v);
  return (u & 0x80000000u) ? ~u : (u | 0x80000000u);   // order-preserving f32->u32
}

__device__ __forceinline__ void proc4(
    float4 x, int j4, float inv_t, float4* __restrict__ o4,
    float& s0, float& s1, float& s2, float& s3,
    unsigned int* nc, float* cv, int* ci)
{
  float vx = x.x*inv_t, vy = x.y*inv_t, vz = x.z*inv_t, vw = x.w*inv_t;
  f32x4 v = {vx, vy, vz, vw};
  *(f32x4*)&o4[j4] = v;
  s0 += __expf(vx); s1 += __expf(vy); s2 += __expf(vz); s3 += __expf(vw);
  // rare branch (p~0.003/elem)
  if (x.x > T0) { unsigned q = atomicAdd(nc,1u); if (q<LCAP){cv[q]=vx; ci[q]=4*j4+0;} }
  if (x.y > T0) { unsigned q = atomicAdd(nc,1u); if (q<LCAP){cv[q]=vy; ci[q]=4*j4+1;} }
  if (x.z > T0) { unsigned q = atomicAdd(nc,1u); if (q<LCAP){cv[q]=vz; ci[q]=4*j4+2;} }
  if (x.w > T0) { unsigned q = atomicAdd(nc,1u); if (q<LCAP){cv[q]=vw; ci[q]=4*j4+3;} }
}

__global__ __launch_bounds__(BS, 8) void stream_kernel(
    const float* __restrict__ logits, const float* __restrict__ temps,
    float* __restrict__ out, unsigned int* __restrict__ cnt,
    float* __restrict__ psum, float* __restrict__ cval, int* __restrict__ cidx)
{
  const int blk = blockIdx.x;
  const int row = blk >> 1;
  const int hh  = blk & 1;
  const int tid = threadIdx.x;

  __shared__ float lcv[LCAP]; __shared__ int lci[LCAP];
  __shared__ float wsum[BS / 64];
  __shared__ unsigned int nc_sh, base_sh;

  if (tid == 0) nc_sh = 0u;
  __syncthreads();

  const float temp  = temps[row];
  const float inv_t = 1.0f / ((temp == 0.0f) ? 1.0f : temp);

  const float4* __restrict__ lg4 =
      reinterpret_cast<const float4*>(logits + (size_t)row * VOCAB);
  float4* __restrict__ o4 =
      reinterpret_cast<float4*>(out + NROW + (size_t)row * VOCAB);

  float s0 = 0.f, s1 = 0.f, s2 = 0.f, s3 = 0.f;

  // ---- stream half-row: scale+write, sum-exp, threshold-collect ----
  int j = hh * H4 + tid;
  #pragma unroll
  for (int g = 0; g < 7; ++g) {            // 7 pairs = 14 iters
    float4 a = lg4[j];
    float4 b = lg4[j + BS];
    proc4(a, j,      inv_t, o4, s0,s1,s2,s3, &nc_sh, lcv, lci);
    proc4(b, j + BS, inv_t, o4, s0,s1,s2,s3, &nc_sh, lcv, lci);
    j += 2 * BS;
  }
  {                                        // 15th iter
    float4 a = lg4[j];
    proc4(a, j, inv_t, o4, s0,s1,s2,s3, &nc_sh, lcv, lci);
  }
  if (tid < TAILT) {                       // tail 640 float4
    int jt = hh * H4 + 15 * BS + tid;
    float4 a = lg4[jt];
    proc4(a, jt, inv_t, o4, s0,s1,s2,s3, &nc_sh, lcv, lci);
  }

  // ---- block sum-exp reduce -> psum (fixed order, deterministic) ----
  float s = (s0 + s1) + (s2 + s3);
  #pragma unroll
  for (int off = 32; off > 0; off >>= 1) s += __shfl_down(s, off);
  if ((tid & 63) == 0) wsum[tid >> 6] = s;
  __syncthreads();
  if (tid == 0) {
    float t = 0.f;
    #pragma unroll
    for (int w = 0; w < BS / 64; ++w) t += wsum[w];
    psum[row * HPR + hh] = t;
    base_sh = atomicAdd(&cnt[row], (nc_sh < (unsigned)LCAP) ? nc_sh : (unsigned)LCAP);
  }
  __syncthreads();

  // ---- coalesced flush of LDS candidates to per-row global list ----
  const int nloc = ((int)nc_sh < LCAP) ? (int)nc_sh : LCAP;
  const unsigned base = base_sh;
  for (int i = tid; i < nloc; i += BS) {
    unsigned p = base + i;
    if (p < CAP) { cval[row * CAP + p] = lcv[i]; cidx[row * CAP + p] = lci[i]; }
  }
  // no fence: the kernel boundary is the coherence point
}

__global__ __launch_bounds__(BSM) void merge_kernel(
    const float* __restrict__ logits, const float* __restrict__ temps,
    const float* __restrict__ topps, const float* __restrict__ topks,
    const float* __restrict__ noise, float* __restrict__ out,
    const unsigned int* __restrict__ cnt, const float* __restrict__ psum,
    const float* __restrict__ cval, const int* __restrict__ cidx)
{
  const int row = blockIdx.x;
  const int tid = threadIdx.x;

  __shared__ float cv2[CAP]; __shared__ int ci2[CAP];
  __shared__ unsigned long long kv[CAP];
  __shared__ float sv[64];   __shared__ int si[64];
  __shared__ float sp_s[64], sc_s[64], noi_s[64];
  __shared__ unsigned int nc2;

  if (tid < 64) noi_s[tid] = noise[(size_t)row * VOCAB + tid];

  const float temp  = temps[row];
  const float inv_t = 1.0f / ((temp == 0.0f) ? 1.0f : temp);
  const float S = psum[row * HPR + 0] + psum[row * HPR + 1];  // fixed order

  int total = (int)cnt[row];
  int n = (total < CAP) ? total : CAP;
  for (int i = tid; i < n; i += BSM) {
    cv2[i] = cval[row * CAP + i];
    ci2[i] = cidx[row * CAP + i];
  }
  __syncthreads();

  // robustness ladder (dead for bench data): rescan full L3-warm row
  float thr = T0;
  for (int att = 0; att < 4 && (total < TOPC || total > CAP); ++att) {
    thr = (total > CAP) ? (thr + 2.0f) : (thr - 4.0f);
    __syncthreads();
    if (tid == 0) nc2 = 0u;
    __syncthreads();
    const float* __restrict__ lg = logits + (size_t)row * VOCAB;
    for (int k = tid; k < VOCAB; k += BSM) {
      float x = lg[k];
      if (x > thr) {
        unsigned p = atomicAdd(&nc2, 1u);
        if (p < CAP) { cv2[p] = x * inv_t; ci2[p] = k; }
      }
    }
    __syncthreads();
    total = (int)nc2;
    n = (total < CAP) ? total : CAP;
  }

  // ---- build packed sort keys: ascending u64 == (value desc, index asc) ----
  if (tid < n)
    kv[tid] = ((unsigned long long)(~ordf(cv2[tid])) << 32) | (unsigned)ci2[tid];
  __syncthreads();

  // ---- rank select: one candidate per thread, batched LDS reads ----
  if (tid < n) {
    const unsigned long long me = kv[tid];
    int r = 0;
    #pragma unroll 8
    for (int k = 0; k < n; ++k) r += (int)(kv[k] < me);
    if (r < 64) { sv[r] = cv2[tid]; si[r] = ci2[tid]; }
  }
  __syncthreads();

  const int lim = (n < TOPC) ? n : TOPC;

  // parallel per-slot prob + gumbel score
  if (tid < lim) {
    float sp = __expf(sv[tid]) * (1.0f / S);
    sp_s[tid] = sp;
    float u = noi_s[tid];
    sc_s[tid] = logf(sp) + (-logf(-logf(u)));
  }
  __syncthreads();

  // serial 63-step joint-mask scan + argmax
  if (tid == 0) {
    const float kk = topks[row];
    const float tp = topps[row];
    float cdf = 0.f, best = -INFINITY; int bestj = 0;
    for (int k = 0; k < lim; ++k) {
      if (((float)k < kk) && (cdf <= tp)) {
        float sc = sc_s[k];
        if (sc > best) { best = sc; bestj = k; }
      }
      cdf += sp_s[k];                      // exclusive cumsum semantics
    }
    int token = (n > 0) ? si[bestj] : 0;
    if (temp == 0.0f && n > 0) token = si[0];
    out[row] = (float)token;
  }
}

extern "C" void kernel_launch(void* const* d_in, const int* in_sizes, int n_in,
                              void* d_out, int out_size, void* d_ws, size_t ws_size,
                              hipStream_t stream) {
  const float* logits = (const float*)d_in[0];
  const float* temps  = (const float*)d_in[1];
  const float* topps  = (const float*)d_in[2];
  const float* topks  = (const float*)d_in[3];
  const float* noise  = (const float*)d_in[4];
  float* out = (float*)d_out;

  char* ws = (char*)d_ws;
  unsigned int* cnt = (unsigned int*)(ws);
  float* psum = (float*)(ws + 1024);
  float* cval = (float*)(ws + 4096);
  int*   cidx = (int*)  (ws + 4096 + (size_t)NROW * CAP * 4);

  hipMemsetAsync(cnt, 0, 1024, stream);
  stream_kernel<<<NROW * HPR, BS, 0, stream>>>(logits, temps, out, cnt, psum, cval, cidx);
  merge_kernel<<<NROW, BSM, 0, stream>>>(logits, temps, topps, topks, noise, out,
                                         cnt, psum, cval, cidx);
}